// Round 8
// baseline (38151.520 us; speedup 1.0000x reference)
//
#include <hip/hip_runtime.h>
#include <hip/hip_cooperative_groups.h>
#include <math.h>

namespace cg = cooperative_groups;

#define NB 64      // batch
#define NT 512     // time steps
#define NE 512     // embed dim
#define NH 1024    // hidden dim
#define NG 3072    // 3*NH

// =====================================================================
// Kernel 1: x_proj GEMM (Tier A only).
// C[t][b][g] = sum_e X[b][t][e] * Wih[g][e] + bih[g]
// =====================================================================
__global__ __launch_bounds__(256) void xproj_gemm(
    const float* __restrict__ X, const float* __restrict__ W,
    const float* __restrict__ bih, float* __restrict__ C)
{
    __shared__ __align__(16) float As[128 * 36];
    __shared__ __align__(16) float Bs[64 * 36];
    const int tid = threadIdx.x;
    const int m0 = blockIdx.x * 128;
    const int n0 = blockIdx.y * 64;
    const int tx = tid & 15;   // n direction
    const int ty = tid >> 4;   // m direction (0..15)

    float acc[8][4];
#pragma unroll
    for (int i = 0; i < 8; ++i)
#pragma unroll
        for (int j = 0; j < 4; ++j) acc[i][j] = 0.f;

    const int a_r = tid >> 1;
    const int a_h = tid & 1;
    const int b_r = tid >> 2;
    const int b_q = tid & 3;

    for (int kc = 0; kc < NE; kc += 32) {
        __syncthreads();
#pragma unroll
        for (int i = 0; i < 4; ++i) {
            int c = (a_h * 4 + i) * 4;
            float4 v = *(const float4*)(X + (size_t)(m0 + a_r) * NE + kc + c);
            *(float4*)(As + a_r * 36 + c) = v;
        }
#pragma unroll
        for (int i = 0; i < 2; ++i) {
            int c = (b_q * 2 + i) * 4;
            float4 v = *(const float4*)(W + (size_t)(n0 + b_r) * NE + kc + c);
            *(float4*)(Bs + b_r * 36 + c) = v;
        }
        __syncthreads();

#pragma unroll
        for (int k4 = 0; k4 < 8; ++k4) {
            float4 av[8], bv[4];
#pragma unroll
            for (int i = 0; i < 8; ++i)
                av[i] = *(const float4*)(As + (i * 16 + ty) * 36 + k4 * 4);
#pragma unroll
            for (int j = 0; j < 4; ++j)
                bv[j] = *(const float4*)(Bs + (j * 16 + tx) * 36 + k4 * 4);
#pragma unroll
            for (int i = 0; i < 8; ++i)
#pragma unroll
                for (int j = 0; j < 4; ++j) {
                    acc[i][j] += av[i].x * bv[j].x + av[i].y * bv[j].y +
                                 av[i].z * bv[j].z + av[i].w * bv[j].w;
                }
        }
    }

#pragma unroll
    for (int j = 0; j < 4; ++j) {
        int n = n0 + j * 16 + tx;
        float bias = bih[n];
#pragma unroll
        for (int i = 0; i < 8; ++i) {
            int m = m0 + i * 16 + ty;
            int bb = m >> 9;        // / NT
            int tt = m & (NT - 1);  // % NT
            C[(size_t)(tt * NB + bb) * NG + n] = acc[i][j] + bias;
        }
    }
}

// =====================================================================
// Kernel 2: GRU recurrence (cooperative, one grid sync per step).
// MODE 0: read precomputed xproj[t][b][3H] (f32) from ws.
// MODE 2: fused — W_ih rows in LDS, compute x-projections on the fly.
// 256 WGs x 256 threads. WG w owns hidden cols j0=4w..4w+3.
// Thread (b = tid>>2, j = tid&3).
// =====================================================================
template <int MODE>
__global__ __launch_bounds__(256) void gru_rec_t(
    const float* __restrict__ xproj,   // [NT][NB][NG]  (MODE 0)
    const float* __restrict__ X,       // [NB][NT][NE]  (MODE 2)
    const float* __restrict__ Wih,     // [NG][NE]      (MODE 2)
    const float* __restrict__ Whh,     // [NG][NH]
    const float* __restrict__ bih,     // [NG]          (MODE 2)
    const float* __restrict__ bhh,     // [NG]
    const int*   __restrict__ seqlen,  // [NB]
    float* __restrict__ hbufs)         // [2][NB][NH]
{
    extern __shared__ float smem[];
    float* Ws = smem;                        // [12][1032]
    float* hs = smem + 12 * 1032;            // [64][260]
    float* Wi = smem + 12 * 1032 + 64 * 260; // [12][520]  (MODE 2 only)

    const int tid = threadIdx.x;
    const int j0 = blockIdx.x * 4;

    // Persistent W_hh slice: rows {g*NH + j0 + j}, padded stride 1032.
#pragma unroll
    for (int row = 0; row < 12; ++row) {
        int g = row >> 2, jj = row & 3;
        float4 v = *(const float4*)(Whh + (size_t)(g * NH + j0 + jj) * NH + tid * 4);
        *(float4*)(Ws + row * 1032 + tid * 4) = v;
    }
    if (MODE == 2) {
        // Persistent W_ih slice: 12 rows x 512, padded stride 520.
#pragma unroll
        for (int row = 0; row < 12; ++row) {
            int g = row >> 2, jj = row & 3;
            if (tid < 128) {
                float4 v = *(const float4*)(Wih + (size_t)(g * NH + j0 + jj) * NE + tid * 4);
                *(float4*)(Wi + row * 520 + tid * 4) = v;
            }
        }
    }
    // RACE FIX: Wi is staged by tid<128 but read by ALL threads at t=0
    // before the kc-loop's first barrier. Barrier before first use.
    __syncthreads();

    const int b = tid >> 2;
    const int j = tid & 3;
    const int jg = j0 + j;
    const int slen = seqlen[b];
    const float br = bhh[jg], bz = bhh[NH + jg], bn = bhh[2 * NH + jg];
    float bir = 0.f, biz = 0.f, bin = 0.f;
    if (MODE == 2) { bir = bih[jg]; biz = bih[NH + jg]; bin = bih[2 * NH + jg]; }

    cg::grid_group grid = cg::this_grid();
    // buffer 0 zeroed by hipMemsetAsync before launch (h0 = 0)

    for (int t = 0; t < NT; ++t) {
        const float* hp = hbufs + (size_t)(t & 1) * (NB * NH);
        float* hn = hbufs + (size_t)((t + 1) & 1) * (NB * NH);

        float xr, xz, xn;
        if (MODE == 0) {
            const size_t xrow = (size_t)(t * NB + b) * NG;
            xr = xproj[xrow + jg];
            xz = xproj[xrow + NH + jg];
            xn = xproj[xrow + 2 * NH + jg];
        } else {
            // Fused input projection: dot(X[b][t][:], Wih rows) from LDS.
            xr = bir; xz = biz; xn = bin;
            const float4* xv4 = (const float4*)(X + ((size_t)b * NT + t) * NE);
            const float4* wir = (const float4*)(Wi + (0 * 4 + j) * 520);
            const float4* wiz = (const float4*)(Wi + (1 * 4 + j) * 520);
            const float4* win = (const float4*)(Wi + (2 * 4 + j) * 520);
#pragma unroll 4
            for (int k = 0; k < 128; ++k) {
                float4 xv = xv4[k];
                float4 a = wir[k];
                xr += xv.x * a.x + xv.y * a.y + xv.z * a.z + xv.w * a.w;
                a = wiz[k];
                xz += xv.x * a.x + xv.y * a.y + xv.z * a.z + xv.w * a.w;
                a = win[k];
                xn += xv.x * a.x + xv.y * a.y + xv.z * a.z + xv.w * a.w;
            }
        }
        float hold = hp[(size_t)b * NH + jg];

        float accr = 0.f, accz = 0.f, accn = 0.f;
        for (int kc = 0; kc < NH; kc += 256) {
            __syncthreads();   // protect hs reuse
#pragma unroll
            for (int i = 0; i < 16; ++i) {
                int col = (tid & 3) * 64 + i * 4;
                float4 v = *(const float4*)(hp + (size_t)(tid >> 2) * NH + kc + col);
                *(float4*)(hs + (tid >> 2) * 260 + col) = v;
            }
            __syncthreads();

            const float4* h4 = (const float4*)(hs + b * 260);
            const float4* wr = (const float4*)(Ws + (0 * 4 + j) * 1032 + kc);
            const float4* wz = (const float4*)(Ws + (1 * 4 + j) * 1032 + kc);
            const float4* wn = (const float4*)(Ws + (2 * 4 + j) * 1032 + kc);
#pragma unroll 8
            for (int k4 = 0; k4 < 64; ++k4) {
                float4 hv = h4[k4];
                float4 wv = wr[k4];
                accr += hv.x * wv.x + hv.y * wv.y + hv.z * wv.z + hv.w * wv.w;
                wv = wz[k4];
                accz += hv.x * wv.x + hv.y * wv.y + hv.z * wv.z + hv.w * wv.w;
                wv = wn[k4];
                accn += hv.x * wv.x + hv.y * wv.y + hv.z * wv.z + hv.w * wv.w;
            }
        }

        float r = 1.f / (1.f + __expf(-(xr + accr + br)));
        float z = 1.f / (1.f + __expf(-(xz + accz + bz)));
        float n = tanhf(xn + r * (accn + bn));
        float hnew = (1.f - z) * n + z * hold;

        hn[(size_t)b * NH + jg] = (t < slen) ? hnew : hold;

        grid.sync();
    }
}

// =====================================================================
// Kernel 2b (FALLBACK if cooperative launch unsupported): one GRU step.
// Same decomposition, but W_hh / W_ih read from global (L2-resident);
// stream ordering between the 512 launches replaces grid.sync().
// =====================================================================
template <int MODE>
__global__ __launch_bounds__(256) void gru_step_t(
    const float* __restrict__ xproj,   // [NT][NB][NG]  (MODE 0)
    const float* __restrict__ X,       // [NB][NT][NE]  (MODE 2)
    const float* __restrict__ Wih,     // [NG][NE]      (MODE 2)
    const float* __restrict__ Whh,     // [NG][NH]
    const float* __restrict__ bih,     // [NG]          (MODE 2)
    const float* __restrict__ bhh,     // [NG]
    const int*   __restrict__ seqlen,  // [NB]
    float* __restrict__ hbufs,         // [2][NB][NH]
    int t)
{
    extern __shared__ float smem[];
    float* hs = smem;                  // [64][260]

    const int tid = threadIdx.x;
    const int j0 = blockIdx.x * 4;
    const int b = tid >> 2;
    const int j = tid & 3;
    const int jg = j0 + j;

    const float* hp = hbufs + (size_t)(t & 1) * (NB * NH);
    float* hn = hbufs + (size_t)((t + 1) & 1) * (NB * NH);

    float xr, xz, xn;
    if (MODE == 0) {
        const size_t xrow = (size_t)(t * NB + b) * NG;
        xr = xproj[xrow + jg];
        xz = xproj[xrow + NH + jg];
        xn = xproj[xrow + 2 * NH + jg];
    } else {
        xr = bih[jg]; xz = bih[NH + jg]; xn = bih[2 * NH + jg];
        const float4* xv4 = (const float4*)(X + ((size_t)b * NT + t) * NE);
        const float4* wir = (const float4*)(Wih + (size_t)jg * NE);
        const float4* wiz = (const float4*)(Wih + (size_t)(NH + jg) * NE);
        const float4* win = (const float4*)(Wih + (size_t)(2 * NH + jg) * NE);
#pragma unroll 4
        for (int k = 0; k < 128; ++k) {
            float4 xv = xv4[k];
            float4 a = wir[k];
            xr += xv.x * a.x + xv.y * a.y + xv.z * a.z + xv.w * a.w;
            a = wiz[k];
            xz += xv.x * a.x + xv.y * a.y + xv.z * a.z + xv.w * a.w;
            a = win[k];
            xn += xv.x * a.x + xv.y * a.y + xv.z * a.z + xv.w * a.w;
        }
    }
    float hold = hp[(size_t)b * NH + jg];

    float accr = 0.f, accz = 0.f, accn = 0.f;
    for (int kc = 0; kc < NH; kc += 256) {
        __syncthreads();
#pragma unroll
        for (int i = 0; i < 16; ++i) {
            int col = (tid & 3) * 64 + i * 4;
            float4 v = *(const float4*)(hp + (size_t)(tid >> 2) * NH + kc + col);
            *(float4*)(hs + (tid >> 2) * 260 + col) = v;
        }
        __syncthreads();

        const float4* h4 = (const float4*)(hs + b * 260);
        const float4* wr = (const float4*)(Whh + (size_t)jg * NH + kc);
        const float4* wz = (const float4*)(Whh + (size_t)(NH + jg) * NH + kc);
        const float4* wn = (const float4*)(Whh + (size_t)(2 * NH + jg) * NH + kc);
#pragma unroll 8
        for (int k4 = 0; k4 < 64; ++k4) {
            float4 hv = h4[k4];
            float4 wv = wr[k4];
            accr += hv.x * wv.x + hv.y * wv.y + hv.z * wv.z + hv.w * wv.w;
            wv = wz[k4];
            accz += hv.x * wv.x + hv.y * wv.y + hv.z * wv.z + hv.w * wv.w;
            wv = wn[k4];
            accn += hv.x * wv.x + hv.y * wv.y + hv.z * wv.z + hv.w * wv.w;
        }
    }

    const int slen = seqlen[b];
    float r = 1.f / (1.f + __expf(-(xr + accr + bhh[jg])));
    float z = 1.f / (1.f + __expf(-(xz + accz + bhh[NH + jg])));
    float n = tanhf(xn + r * (accn + bhh[2 * NH + jg]));
    float hnew = (1.f - z) * n + z * hold;

    hn[(size_t)b * NH + jg] = (t < slen) ? hnew : hold;
}

// =====================================================================
// Kernel 3: out[b] = sigmoid(dot(h_final[b], W_out) + b_out)
// =====================================================================
__global__ __launch_bounds__(256) void out_kernel(
    const float* __restrict__ hfin,
    const float* __restrict__ Wout,
    const float* __restrict__ bout,
    float* __restrict__ out)
{
    const int b = blockIdx.x;
    const int tid = threadIdx.x;
    float4 h = *(const float4*)(hfin + (size_t)b * NH + tid * 4);
    float4 w = *(const float4*)(Wout + tid * 4);
    float p = h.x * w.x + h.y * w.y + h.z * w.z + h.w * w.w;
#pragma unroll
    for (int off = 32; off; off >>= 1) p += __shfl_down(p, off);
    __shared__ float red[4];
    if ((tid & 63) == 0) red[tid >> 6] = p;
    __syncthreads();
    if (tid == 0) {
        float s = red[0] + red[1] + red[2] + red[3] + bout[0];
        out[b] = 1.f / (1.f + __expf(-s));
    }
}

// =====================================================================
extern "C" void kernel_launch(void* const* d_in, const int* in_sizes, int n_in,
                              void* d_out, int out_size, void* d_ws, size_t ws_size,
                              hipStream_t stream) {
    const float* x    = (const float*)d_in[0];
    const int*   slen = (const int*)d_in[1];
    const float* Wih  = (const float*)d_in[2];
    const float* Whh  = (const float*)d_in[3];
    const float* bih  = (const float*)d_in[4];
    const float* bhh  = (const float*)d_in[5];
    const float* Wout = (const float*)d_in[6];
    const float* bout = (const float*)d_in[7];
    float* out = (float*)d_out;

    const size_t xproj_elems = (size_t)NT * NB * NG;                // 100.66M
    const size_t hbuf_bytes  = (size_t)2 * NB * NH * sizeof(float); // 512 KB
    const size_t needA = xproj_elems * sizeof(float) + hbuf_bytes;  // 403.2 MB

    const bool tierA = (ws_size >= needA);

    float* xproj;
    float* hbufs;
    if (tierA) {
        xproj = (float*)d_ws;
        hbufs = xproj + xproj_elems;
    } else {
        xproj = nullptr;               // unused in fused mode
        hbufs = (float*)d_ws;          // needs only 512 KB
    }

    // h0 = 0 (ws is poisoned 0xAA before every timed call)
    hipMemsetAsync(hbufs, 0, hbuf_bytes, stream);

    if (tierA) {
        dim3 g1(NB * NT / 128, NG / 64);
        xproj_gemm<<<g1, 256, 0, stream>>>(x, Wih, bih, xproj);
    }

    const size_t smemA = (size_t)(12 * 1032 + 64 * 260) * sizeof(float);            // 116096 B
    const size_t smemC = (size_t)(12 * 1032 + 64 * 260 + 12 * 520) * sizeof(float); // 141056 B
    const void* kfn = tierA ? (const void*)&gru_rec_t<0> : (const void*)&gru_rec_t<2>;
    const size_t smem = tierA ? smemA : smemC;
    hipFuncSetAttribute(kfn, hipFuncAttributeMaxDynamicSharedMemorySize, (int)smem);

    const float* xp_c  = xproj;
    const float* x_c   = x;
    const float* Wih_c = Wih;
    const float* Whh_c = Whh;
    const float* bih_c = bih;
    const float* bhh_c = bhh;
    const int*   sl_c  = slen;
    float*       hb_c  = hbufs;
    void* args[] = { (void*)&xp_c, (void*)&x_c, (void*)&Wih_c, (void*)&Whh_c,
                     (void*)&bih_c, (void*)&bhh_c, (void*)&sl_c, (void*)&hb_c };
    hipError_t cerr = hipLaunchCooperativeKernel(kfn, dim3(256), dim3(256),
                                                 args, (unsigned int)smem, stream);

    if (cerr != hipSuccess) {
        // Fallback: 512 per-step launches (stream ordering = dependency).
        const size_t smemS = (size_t)(64 * 260) * sizeof(float); // 66560 B
        if (tierA) {
            hipFuncSetAttribute((const void*)&gru_step_t<0>,
                                hipFuncAttributeMaxDynamicSharedMemorySize, (int)smemS);
            for (int t = 0; t < NT; ++t)
                gru_step_t<0><<<256, 256, smemS, stream>>>(
                    xproj, x, Wih, Whh, bih, bhh, slen, hbufs, t);
        } else {
            hipFuncSetAttribute((const void*)&gru_step_t<2>,
                                hipFuncAttributeMaxDynamicSharedMemorySize, (int)smemS);
            for (int t = 0; t < NT; ++t)
                gru_step_t<2><<<256, 256, smemS, stream>>>(
                    xproj, x, Wih, Whh, bih, bhh, slen, hbufs, t);
        }
    }

    out_kernel<<<NB, 256, 0, stream>>>(hbufs, Wout, bout, out);
}